// Round 4
// baseline (137.034 us; speedup 1.0000x reference)
//
#include <hip/hip_runtime.h>
#include <hip/hip_bf16.h>
#include <math.h>

// CrossAttention3D: B=1, C=64, N=4096, 8 heads x hd=8.
// MFMA plan (32x32x16 bf16, fp32 accum):
//   QK:  D = A(K)xB(Q) = S^T tile [32k x 32q]; kslots 8-15 zeroed via zero-page.
//   softmax: no max subtraction (|logit| <~ 2.6 base-2); p = exp2(s).
//   PV:  A = P (LDS round-trip, 72B pitch), B = VtP pre-swizzled into exact
//        MFMA B-frag order -> each frag load is one coalesced 1KB burst
//        (R3's row-scattered Vt loads hit ~32 cache lines per instr).
//        VtP row d=8 = ones -> D col 8 = softmax denominator for free.
//   split-K KS=16 over blockIdx.z; linear combine (no max -> partials sum).

#define N_VOX 4096
#define NH 8
#define QSCALE 0.51010813f  // 8^-0.5 * log2(e)

typedef unsigned short ushort_t;
typedef __attribute__((ext_vector_type(8))) short bf16x8;
typedef __attribute__((ext_vector_type(16))) float f32x16;

__device__ __forceinline__ unsigned short f2bf(float f) {
  union { float f; unsigned u; } v; v.f = f;
  unsigned r = v.u + 0x7FFFu + ((v.u >> 16) & 1u);
  return (unsigned short)(r >> 16);
}
__device__ __forceinline__ unsigned pk2bf(float a, float b) {
  __hip_bfloat162 h = __float22bfloat162_rn(float2{a, b});
  union { __hip_bfloat162 h; unsigned u; } c; c.h = h;
  return c.u;
}
__device__ __forceinline__ float ex2(float x) { return __builtin_amdgcn_exp2f(x); }

// ---------------------------------------------------------------------------
// Projections -> packed bf16 operand layouts.
// grid (16, 16) x 256: bx 0-7 = Q(dec) head; 8-15 = K+V(mae) head.
// VtP layout: [h][kb = key/16][lane 0-63][j 0-7] ushort, where element =
//   V^T[d = lane&31][key = kb*16 + (lane>>5)*8 + j]; d==8 -> 1.0 (denominator
//   row); d=9..31 left as ws poison (finite 0xAAAA, lands in discarded D cols).
__global__ __launch_bounds__(256) void qkv_pack(
    const float* __restrict__ dec, const float* __restrict__ mae,
    const float* __restrict__ qw, const float* __restrict__ qb_,
    const float* __restrict__ kw, const float* __restrict__ kb,
    const float* __restrict__ vw, const float* __restrict__ vb,
    ushort_t* __restrict__ Qp, ushort_t* __restrict__ Kp,
    ushort_t* __restrict__ VtP, ushort_t* __restrict__ zeroblk) {
  const int bx = blockIdx.x;
  const int n = blockIdx.y * 256 + threadIdx.x;

  if (bx < 8) {
    const int h = bx;
    float x[64];
#pragma unroll
    for (int c = 0; c < 64; ++c) x[c] = dec[c * N_VOX + n];
    float qv[8];
#pragma unroll
    for (int j = 0; j < 8; ++j) {
      const int o = h * 8 + j;
      float a = qb_[o];
#pragma unroll
      for (int c = 0; c < 64; ++c) a = fmaf(x[c], qw[o * 64 + c], a);
      qv[j] = a * QSCALE;
    }
    uint4 pk;
    pk.x = pk2bf(qv[0], qv[1]); pk.y = pk2bf(qv[2], qv[3]);
    pk.z = pk2bf(qv[4], qv[5]); pk.w = pk2bf(qv[6], qv[7]);
    *(uint4*)(Qp + ((size_t)h * N_VOX + n) * 8) = pk;
  } else {
    const int h = bx - 8;
    float x[64];
#pragma unroll
    for (int c = 0; c < 64; ++c) x[c] = mae[c * N_VOX + n];
    float kv[8], vv[8];
#pragma unroll
    for (int j = 0; j < 8; ++j) {
      const int o = h * 8 + j;
      float a = kb[o], b = vb[o];
#pragma unroll
      for (int c = 0; c < 64; ++c) {
        a = fmaf(x[c], kw[o * 64 + c], a);
        b = fmaf(x[c], vw[o * 64 + c], b);
      }
      kv[j] = a; vv[j] = b;
    }
    uint4 pk;
    pk.x = pk2bf(kv[0], kv[1]); pk.y = pk2bf(kv[2], kv[3]);
    pk.z = pk2bf(kv[4], kv[5]); pk.w = pk2bf(kv[6], kv[7]);
    *(uint4*)(Kp + ((size_t)h * N_VOX + n) * 8) = pk;

    // VtP scatter: lane = ((n>>3)&1)*32 + d, j = n&7, kb = n>>4.
    const size_t base =
        (((size_t)h * (N_VOX / 16) + (n >> 4)) * 64 + ((n >> 3) & 1) * 32) * 8 +
        (n & 7);
#pragma unroll
    for (int d = 0; d < 8; ++d) VtP[base + (size_t)d * 8] = f2bf(vv[d]);
    VtP[base + 8 * 8] = 0x3F80;           // ones row -> denominator
    if (h == 0 && n < 8) zeroblk[n] = 0;  // zero page for K kslots 8-15
  }
}

// ---------------------------------------------------------------------------
// Fused attention, MFMA. grid (16, 8, KS) x 256 (4 waves; wave = 64 q).
__global__ __launch_bounds__(256, 4) void attn_mfma(
    const ushort_t* __restrict__ Qp, const ushort_t* __restrict__ Kp,
    const ushort_t* __restrict__ VtP, const ushort_t* __restrict__ zeroblk,
    float* __restrict__ o_part, int kps) {
  const int tid = threadIdx.x;
  const int lane = tid & 63;
  const int wave = tid >> 6;
  const int l31 = lane & 31;
  const int lhalf = lane >> 5;
  const int h = blockIdx.y;
  const int ks = blockIdx.z;
  const int qb = blockIdx.x * 256 + wave * 64;

  // P scratch: [wave*2+qtile][q=32 rows][36 ushorts] (72 B pitch -> <=2-way
  // bank aliasing on b64 ops, free per m136).
  __shared__ ushort_t P_lds[8][32 * 36];

  bf16x8 qfrag0 = *(const bf16x8*)(Qp + ((size_t)h * N_VOX + qb + l31) * 8);
  bf16x8 qfrag1 = *(const bf16x8*)(Qp + ((size_t)h * N_VOX + qb + 32 + l31) * 8);

  f32x16 zf, acc0, acc1;
#pragma unroll
  for (int i = 0; i < 16; ++i) { zf[i] = 0.f; acc0[i] = 0.f; acc1[i] = 0.f; }

  const ushort_t* KpH = Kp + (size_t)h * N_VOX * 8;
  const ushort_t* VtPH = VtP + (size_t)h * (N_VOX / 16) * 64 * 8;
  ushort_t* pb0 = &P_lds[wave * 2 + 0][l31 * 36];
  ushort_t* pb1 = &P_lds[wave * 2 + 1][l31 * 36];

  const int kbeg = ks * kps;
  const ushort_t* kzero = zeroblk;

  // Prefetch iter 0 fragments.
  bf16x8 kf = *(const bf16x8*)(lhalf ? kzero
                                     : (KpH + (size_t)(kbeg + l31) * 8));
  bf16x8 vf0 = *(const bf16x8*)(VtPH + ((size_t)((kbeg >> 4) + 0) * 64 + lane) * 8);
  bf16x8 vf1 = *(const bf16x8*)(VtPH + ((size_t)((kbeg >> 4) + 1) * 64 + lane) * 8);

  for (int kk = 0; kk < kps; kk += 32) {
    // Prefetch next iteration (clamped; last iter reloads current).
    const int knext = (kk + 32 < kps) ? (kbeg + kk + 32) : (kbeg + kk);
    bf16x8 kf_n = *(const bf16x8*)(lhalf ? kzero
                                         : (KpH + (size_t)(knext + l31) * 8));
    bf16x8 vf0_n = *(const bf16x8*)(VtPH + ((size_t)((knext >> 4) + 0) * 64 + lane) * 8);
    bf16x8 vf1_n = *(const bf16x8*)(VtPH + ((size_t)((knext >> 4) + 1) * 64 + lane) * 8);

    f32x16 s0 = __builtin_amdgcn_mfma_f32_32x32x16_bf16(kf, qfrag0, zf, 0, 0, 0);
    f32x16 s1 = __builtin_amdgcn_mfma_f32_32x32x16_bf16(kf, qfrag1, zf, 0, 0, 0);

    // p = exp2(s); store P[q][key_local] (lane col = q; rows = keys).
#pragma unroll
    for (int G = 0; G < 4; ++G) {
      uint2 w;
      w.x = pk2bf(ex2(s0[G * 4 + 0]), ex2(s0[G * 4 + 1]));
      w.y = pk2bf(ex2(s0[G * 4 + 2]), ex2(s0[G * 4 + 3]));
      *(uint2*)(pb0 + G * 8 + lhalf * 4) = w;
    }
#pragma unroll
    for (int G = 0; G < 4; ++G) {
      uint2 w;
      w.x = pk2bf(ex2(s1[G * 4 + 0]), ex2(s1[G * 4 + 1]));
      w.y = pk2bf(ex2(s1[G * 4 + 2]), ex2(s1[G * 4 + 3]));
      *(uint2*)(pb1 + G * 8 + lhalf * 4) = w;
    }

    // PV: A = P[m=q][k=key_local], B = VtP frag.
#pragma unroll
    for (int grp = 0; grp < 2; ++grp) {
      union { bf16x8 v; uint2 u[2]; } p0, p1;
      p0.u[0] = *(const uint2*)(pb0 + grp * 16 + lhalf * 8);
      p0.u[1] = *(const uint2*)(pb0 + grp * 16 + lhalf * 8 + 4);
      p1.u[0] = *(const uint2*)(pb1 + grp * 16 + lhalf * 8);
      p1.u[1] = *(const uint2*)(pb1 + grp * 16 + lhalf * 8 + 4);
      const bf16x8 vf = grp ? vf1 : vf0;
      acc0 = __builtin_amdgcn_mfma_f32_32x32x16_bf16(p0.v, vf, acc0, 0, 0, 0);
      acc1 = __builtin_amdgcn_mfma_f32_32x32x16_bf16(p1.v, vf, acc1, 0, 0, 0);
    }

    kf = kf_n; vf0 = vf0_n; vf1 = vf1_n;
  }

  // Epilogue: D col (l31) = d 0-7, col 8 = l; rows = q.
  if (l31 < 9) {
    float* ob = o_part + ((size_t)(ks * NH + h) * 9 + l31) * N_VOX;
#pragma unroll
    for (int t = 0; t < 2; ++t) {
      const f32x16 a = t ? acc1 : acc0;
      const int qst = qb + t * 32 + 4 * lhalf;
#pragma unroll
      for (int G = 0; G < 4; ++G) {
        float4 v4 = make_float4(a[G * 4 + 0], a[G * 4 + 1], a[G * 4 + 2], a[G * 4 + 3]);
        *(float4*)(ob + qst + 8 * G) = v4;
      }
    }
  }
}

// ---------------------------------------------------------------------------
// Combine split-K partials: ocomb[c][n] = sum_o / sum_l.  grid 1024 x 256.
__global__ __launch_bounds__(256) void combine(
    const float* __restrict__ o_part, float* __restrict__ ocomb, int KS) {
  const int t = blockIdx.x * 256 + threadIdx.x;
  const int c = t >> 12, n = t & (N_VOX - 1);
  const int h = c >> 3, d = c & 7;
  float so = 0.f, sl = 0.f;
  for (int s = 0; s < KS; ++s) {
    const float* base = o_part + ((size_t)(s * NH + h) * 9) * N_VOX;
    so += base[d * N_VOX + n];
    sl += base[8 * N_VOX + n];
  }
  ocomb[(size_t)c * N_VOX + n] = so / sl;
}

// ---------------------------------------------------------------------------
// Output projection (fp32).  grid (8, 16) x 256.
__global__ __launch_bounds__(256) void out_proj(
    const float* __restrict__ ocomb, const float* __restrict__ ow,
    const float* __restrict__ obias, float* __restrict__ out) {
  const int og = blockIdx.x;
  const int n = blockIdx.y * 256 + threadIdx.x;
  float x[64];
#pragma unroll
  for (int c = 0; c < 64; ++c) x[c] = ocomb[c * N_VOX + n];
#pragma unroll
  for (int j = 0; j < 8; ++j) {
    const int o = og * 8 + j;
    float acc = obias[o];
#pragma unroll
    for (int c = 0; c < 64; ++c) acc = fmaf(x[c], ow[o * 64 + c], acc);
    out[o * N_VOX + n] = acc;
  }
}

// ---------------------------------------------------------------------------
extern "C" void kernel_launch(void* const* d_in, const int* in_sizes, int n_in,
                              void* d_out, int out_size, void* d_ws, size_t ws_size,
                              hipStream_t stream) {
  const float* dec = (const float*)d_in[0];
  const float* mae = (const float*)d_in[1];
  const float* qw = (const float*)d_in[2];
  const float* qb = (const float*)d_in[3];
  const float* kw = (const float*)d_in[4];
  const float* kb = (const float*)d_in[5];
  const float* vw = (const float*)d_in[6];
  const float* vb = (const float*)d_in[7];
  const float* ow = (const float*)d_in[8];
  const float* ob = (const float*)d_in[9];
  float* out = (float*)d_out;
  char* ws = (char*)d_ws;

  const size_t OFF_QP = 0;                       // 512 KB
  const size_t OFF_KP = 0x80000;                 // 512 KB
  const size_t OFF_ZERO = 0x100000;              // 4 KB slot
  const size_t OFF_VT = 0x101000;                // VtP: 8*256*64*8*2 = 2 MB
  const size_t OFF_OPART = 0x301000;

  // Largest split-K fitting the workspace (ws_size constant -> graph-safe).
  int KS = 16;
  while (KS > 1) {
    size_t need = OFF_OPART + (size_t)KS * NH * 9 * N_VOX * 4 + 64ull * N_VOX * 4;
    if (need <= ws_size) break;
    KS >>= 1;
  }
  const size_t OFF_OCOMB = OFF_OPART + (size_t)KS * NH * 9 * N_VOX * 4;

  ushort_t* Qp = (ushort_t*)(ws + OFF_QP);
  ushort_t* Kp = (ushort_t*)(ws + OFF_KP);
  ushort_t* zb = (ushort_t*)(ws + OFF_ZERO);
  ushort_t* VtP = (ushort_t*)(ws + OFF_VT);
  float* o_part = (float*)(ws + OFF_OPART);
  float* ocomb = (float*)(ws + OFF_OCOMB);

  qkv_pack<<<dim3(16, 16), 256, 0, stream>>>(dec, mae, qw, qb, kw, kb, vw, vb,
                                             Qp, Kp, VtP, zb);
  attn_mfma<<<dim3(16, 8, KS), 256, 0, stream>>>(Qp, Kp, VtP, zb, o_part,
                                                 N_VOX / KS);
  combine<<<1024, 256, 0, stream>>>(o_part, ocomb, KS);
  out_proj<<<dim3(8, 16), 256, 0, stream>>>(ocomb, ow, ob, out);
}